// Round 1
// baseline (1999.655 us; speedup 1.0000x reference)
//
#include <hip/hip_runtime.h>
#include <stdint.h>

#define BB 8
#define TT 4096
#define DIN 1024
#define DC 256
#define CS 8192
#define EPSF 1e-12f

// ---------------- workspace layout (bytes) ----------------
constexpr size_t OFF_WIN   = 0;                          // w_in:   256*1024 f
constexpr size_t OFF_WOUTT = OFF_WIN   + 262144ull*4;    // w_outT: 256*1024 f  [c][d]
constexpr size_t OFF_CBN   = OFF_WOUTT + 262144ull*4;    // cbn:    8192*256 f (row-major, normalized)
constexpr size_t OFF_NRM2  = OFF_CBN   + 2097152ull*4;   // nrm2:   8192 f
constexpr size_t OFF_ZE    = OFF_NRM2  + 8192ull*4;      // z_e:    8*256*4096 f  [b][c][t]
constexpr size_t OFF_INV   = OFF_ZE    + 8388608ull*4;   // inv:    32768 f
constexpr size_t OFF_ENC2  = OFF_INV   + 32768ull*4;     // enc2:   32768 f
constexpr size_t OFF_KEYS  = OFF_ENC2  + 32768ull*4;     // keys:   32768 u64
constexpr size_t OFF_LOSS  = OFF_KEYS  + 32768ull*8;     // loss:   8 f (+pad)
constexpr size_t OFF_W2T   = OFF_LOSS  + 256;            // W2T:    8192*1024 f [j][d]

// ---------------- helpers ----------------
__device__ __forceinline__ float block_reduce_sum_256(float v, float* sbuf) {
  #pragma unroll
  for (int o = 32; o > 0; o >>= 1) v += __shfl_down(v, o, 64);
  int lane = threadIdx.x & 63, w = threadIdx.x >> 6;
  if (lane == 0) sbuf[w] = v;
  __syncthreads();
  float r = sbuf[0] + sbuf[1] + sbuf[2] + sbuf[3];
  __syncthreads();
  return r;
}

// ---------------- weight prep ----------------
__global__ void k_prep_win(const float* __restrict__ v, const float* __restrict__ g,
                           float* __restrict__ w) {
  __shared__ float sb[4];
  int r = blockIdx.x, t = threadIdx.x;
  float xv[4]; float s = 0.f;
  #pragma unroll
  for (int i = 0; i < 4; i++) { xv[i] = v[r*DIN + t + i*256]; s += xv[i]*xv[i]; }
  s = block_reduce_sum_256(s, sb);
  float sc = g[r] / fmaxf(sqrtf(s), EPSF);
  #pragma unroll
  for (int i = 0; i < 4; i++) w[r*DIN + t + i*256] = xv[i] * sc;
}

__global__ void k_prep_wout(const float* __restrict__ v, const float* __restrict__ g,
                            float* __restrict__ wT) {
  __shared__ float sb[4];
  int r = blockIdx.x, t = threadIdx.x;      // r in [0,1024), t in [0,256)
  float x = v[r*DC + t];
  float s = block_reduce_sum_256(x*x, sb);
  float sc = g[r] / fmaxf(sqrtf(s), EPSF);
  wT[t*DIN + r] = x * sc;
}

__global__ void k_prep_cb(const float* __restrict__ cb, float* __restrict__ cbn,
                          float* __restrict__ nrm2) {
  __shared__ float sb[4];
  int j = blockIdx.x, t = threadIdx.x;      // j in [0,8192), t in [0,256)
  float x = cb[j*DC + t];
  float s = block_reduce_sum_256(x*x, sb);
  float nm = fmaxf(sqrtf(s), EPSF);
  float cn = x / nm;                        // match reference: divide
  cbn[j*DC + t] = cn;
  float q = block_reduce_sum_256(cn*cn, sb);
  if (t == 0) nrm2[j] = q;
}

// ---------------- generic fp32 GEMM: C[m][n] = sum_k A[m][k]*B[k][n] (+bias[m]) ----------------
// tile 128x128, BK=16, 256 threads, 8x8 per thread
template<bool BIAS>
__global__ __launch_bounds__(256) void k_gemm(
    const float* __restrict__ A, const float* __restrict__ Bmat,
    const float* __restrict__ bias, float* __restrict__ C,
    int K, int lda, int ldb, int ldc, size_t strideB, size_t strideC)
{
  __shared__ float As[16][132];
  __shared__ float Bs[16][132];
  const int bn = blockIdx.x * 128;
  const int bm = blockIdx.y * 128;
  const float* Bb = Bmat + (size_t)blockIdx.z * strideB;
  float* Cb = C + (size_t)blockIdx.z * strideC;
  const int tid = threadIdx.x;
  const int tx = tid & 15, ty = tid >> 4;
  const int am = tid & 127, akq = (tid >> 7) * 8;
  const int bk = tid >> 5, bj = (tid & 31) * 4;

  float acc[8][8];
  #pragma unroll
  for (int i = 0; i < 8; i++)
    #pragma unroll
    for (int j = 0; j < 8; j++) acc[i][j] = 0.f;

  for (int k0 = 0; k0 < K; k0 += 16) {
    float4 a0 = *(const float4*)&A[(size_t)(bm+am)*lda + k0 + akq];
    float4 a1 = *(const float4*)&A[(size_t)(bm+am)*lda + k0 + akq + 4];
    float4 b0 = *(const float4*)&Bb[(size_t)(k0+bk)*ldb + bn + bj];
    float4 b1 = *(const float4*)&Bb[(size_t)(k0+bk+8)*ldb + bn + bj];
    As[akq+0][am] = a0.x; As[akq+1][am] = a0.y; As[akq+2][am] = a0.z; As[akq+3][am] = a0.w;
    As[akq+4][am] = a1.x; As[akq+5][am] = a1.y; As[akq+6][am] = a1.z; As[akq+7][am] = a1.w;
    *(float4*)&Bs[bk][bj] = b0;
    *(float4*)&Bs[bk+8][bj] = b1;
    __syncthreads();
    #pragma unroll
    for (int k = 0; k < 16; k++) {
      float av[8], bv[8];
      float4 x0 = *(const float4*)&As[k][tx*4];
      float4 x1 = *(const float4*)&As[k][tx*4+64];
      float4 y0 = *(const float4*)&Bs[k][ty*4];
      float4 y1 = *(const float4*)&Bs[k][ty*4+64];
      av[0]=x0.x; av[1]=x0.y; av[2]=x0.z; av[3]=x0.w;
      av[4]=x1.x; av[5]=x1.y; av[6]=x1.z; av[7]=x1.w;
      bv[0]=y0.x; bv[1]=y0.y; bv[2]=y0.z; bv[3]=y0.w;
      bv[4]=y1.x; bv[5]=y1.y; bv[6]=y1.z; bv[7]=y1.w;
      #pragma unroll
      for (int i = 0; i < 8; i++)
        #pragma unroll
        for (int j = 0; j < 8; j++)
          acc[i][j] += av[i] * bv[j];
    }
    __syncthreads();
  }

  #pragma unroll
  for (int i = 0; i < 8; i++) {
    int m = bm + ((i < 4) ? tx*4 + i : 64 + tx*4 + (i-4));
    float bia = BIAS ? bias[m] : 0.f;
    float4 v0 = make_float4(acc[i][0]+bia, acc[i][1]+bia, acc[i][2]+bia, acc[i][3]+bia);
    float4 v1 = make_float4(acc[i][4]+bia, acc[i][5]+bia, acc[i][6]+bia, acc[i][7]+bia);
    *(float4*)&Cb[(size_t)m*ldc + bn + ty*4]      = v0;
    *(float4*)&Cb[(size_t)m*ldc + bn + 64 + ty*4] = v1;
  }
}

// ---------------- column norms of z_e ----------------
__global__ void k_colnorm(const float* __restrict__ ze, float* __restrict__ inv,
                          float* __restrict__ enc2) {
  int r = blockIdx.x * 256 + threadIdx.x;        // [0, 32768)
  int b = r >> 12, t = r & 4095;
  const float* p = ze + (size_t)b*DC*TT + t;
  float s = 0.f;
  for (int c = 0; c < DC; c++) { float x = p[(size_t)c*TT]; s += x*x; }
  float iv = 1.f / fmaxf(sqrtf(s), EPSF);
  inv[r] = iv;
  enc2[r] = (s * iv) * iv;
}

// ---------------- fused distance + argmin ----------------
// rows: t (128/block), cols: codes j (128/block); K = 256
__global__ __launch_bounds__(256) void k_dist(
    const float* __restrict__ ze, const float* __restrict__ cbn,
    const float* __restrict__ nrm2, const float* __restrict__ inv,
    const float* __restrict__ enc2, unsigned long long* __restrict__ keys)
{
  __shared__ float As[16][132];
  __shared__ float Bs[16][132];
  __shared__ float sInv[128], sNrm2[128], sEnc2[128];
  __shared__ unsigned long long rkey[128];

  const int b  = blockIdx.z;
  const int t0 = blockIdx.y * 128;
  const int j0 = blockIdx.x * 128;
  const int tid = threadIdx.x;

  if (tid < 128) {
    sInv[tid]  = inv[b*TT + t0 + tid];
    sEnc2[tid] = enc2[b*TT + t0 + tid];
    sNrm2[tid] = nrm2[j0 + tid];
    rkey[tid]  = 0xFFFFFFFFFFFFFFFFull;
  }
  __syncthreads();

  const float* zb = ze + (size_t)b*DC*TT;
  const int ak = tid >> 5;            // 0..7
  const int at = (tid & 31) * 4;      // 0..124
  const int bj = tid & 127, bkh = (tid >> 7) * 8;

  float acc[8][8];
  #pragma unroll
  for (int i = 0; i < 8; i++)
    #pragma unroll
    for (int j = 0; j < 8; j++) acc[i][j] = 0.f;

  for (int k0 = 0; k0 < DC; k0 += 16) {
    float4 z0 = *(const float4*)&zb[(size_t)(k0+ak)*TT + t0 + at];
    float4 z1 = *(const float4*)&zb[(size_t)(k0+ak+8)*TT + t0 + at];
    z0.x *= sInv[at]; z0.y *= sInv[at+1]; z0.z *= sInv[at+2]; z0.w *= sInv[at+3];
    z1.x *= sInv[at]; z1.y *= sInv[at+1]; z1.z *= sInv[at+2]; z1.w *= sInv[at+3];
    float4 c0 = *(const float4*)&cbn[(size_t)(j0+bj)*DC + k0 + bkh];
    float4 c1 = *(const float4*)&cbn[(size_t)(j0+bj)*DC + k0 + bkh + 4];
    *(float4*)&As[ak][at]   = z0;
    *(float4*)&As[ak+8][at] = z1;
    Bs[bkh+0][bj] = c0.x; Bs[bkh+1][bj] = c0.y; Bs[bkh+2][bj] = c0.z; Bs[bkh+3][bj] = c0.w;
    Bs[bkh+4][bj] = c1.x; Bs[bkh+5][bj] = c1.y; Bs[bkh+6][bj] = c1.z; Bs[bkh+7][bj] = c1.w;
    __syncthreads();
    const int tx = tid & 15, ty = tid >> 4;
    #pragma unroll
    for (int k = 0; k < 16; k++) {
      float av[8], bv[8];
      float4 x0 = *(const float4*)&As[k][tx*4];
      float4 x1 = *(const float4*)&As[k][tx*4+64];
      float4 y0 = *(const float4*)&Bs[k][ty*4];
      float4 y1 = *(const float4*)&Bs[k][ty*4+64];
      av[0]=x0.x; av[1]=x0.y; av[2]=x0.z; av[3]=x0.w;
      av[4]=x1.x; av[5]=x1.y; av[6]=x1.z; av[7]=x1.w;
      bv[0]=y0.x; bv[1]=y0.y; bv[2]=y0.z; bv[3]=y0.w;
      bv[4]=y1.x; bv[5]=y1.y; bv[6]=y1.z; bv[7]=y1.w;
      #pragma unroll
      for (int i = 0; i < 8; i++)
        #pragma unroll
        for (int j = 0; j < 8; j++)
          acc[i][j] += av[i] * bv[j];
    }
    __syncthreads();
  }

  const int tx = tid & 15, ty = tid >> 4;
  #pragma unroll
  for (int i = 0; i < 8; i++) {
    int tloc = (i < 4) ? tx*4 + i : 64 + tx*4 + (i-4);
    float e2 = sEnc2[tloc];
    unsigned long long best = 0xFFFFFFFFFFFFFFFFull;
    #pragma unroll
    for (int j = 0; j < 8; j++) {
      int jloc = (j < 4) ? ty*4 + j : 64 + ty*4 + (j-4);
      float d = e2 - 2.0f * acc[i][j];   // one rounding (2*acc exact)
      d = d + sNrm2[jloc];
      unsigned long long key =
          ((unsigned long long)__float_as_uint(d) << 32) | (unsigned)(j0 + jloc);
      best = key < best ? key : best;
    }
    atomicMin(&rkey[tloc], best);
  }
  __syncthreads();
  if (tid < 128) atomicMin(&keys[(size_t)b*TT + t0 + tid], rkey[tid]);
}

// ---------------- losses + indices ----------------
__global__ void k_lossidx(const float* __restrict__ ze, const float* __restrict__ cb,
                          const unsigned long long* __restrict__ keys,
                          float* __restrict__ loss_sums, float* __restrict__ out_idx)
{
  __shared__ float sb[4];
  __shared__ int sj[64];
  int b = blockIdx.y, t0 = blockIdx.x * 64;
  int tid = threadIdx.x;
  if (tid < 64) {
    unsigned long long k = keys[(size_t)b*TT + t0 + tid];
    int j = (int)(unsigned)(k & 0xFFFFFFFFull);
    sj[tid] = j;
    out_idx[(size_t)b*TT + t0 + tid] = (float)j;
  }
  __syncthreads();
  int tt = tid & 63, tc = tid >> 6;
  const float* zb = ze + (size_t)b*DC*TT + t0;
  int j = sj[tt];
  float s = 0.f;
  for (int ci = 0; ci < 64; ci++) {
    int c = tc + ci*4;
    float zev = zb[(size_t)c*TT + tt];
    float zqv = cb[(size_t)j*DC + c];
    float d = zev - zqv;
    s += d*d;
  }
  s = block_reduce_sum_256(s, sb);
  if (tid == 0) atomicAdd(&loss_sums[b], s);
}

__global__ void k_losswrite(const float* __restrict__ loss_sums, float* __restrict__ out_loss) {
  int i = threadIdx.x;
  if (i < 8) {
    float v = loss_sums[i] * (1.f/1048576.f);  // exact 2^-20 scale == /mean count
    out_loss[i] = v;
    out_loss[8 + i] = v;
  }
}

// ---------------- output gather: z_q_out[b][d][t] = W2T[j(b,t)][d] + out_b[d] ----------------
__global__ void k_outgather(const float* __restrict__ W2T,
                            const unsigned long long* __restrict__ keys,
                            const float* __restrict__ out_b, float* __restrict__ out)
{
  __shared__ float tile[64][65];
  __shared__ int sj[64];
  int b = blockIdx.y, t0 = blockIdx.x * 64;
  int tid = threadIdx.x;
  if (tid < 64) sj[tid] = (int)(unsigned)(keys[(size_t)b*TT + t0 + tid] & 0xFFFFFFFFull);
  __syncthreads();
  float* ob = out + (size_t)b*DIN*TT;
  int dd = tid & 63, tq = tid >> 6;
  for (int d0 = 0; d0 < DIN; d0 += 64) {
    #pragma unroll
    for (int i = 0; i < 16; i++) {
      int t = tq*16 + i;
      tile[t][dd] = W2T[(size_t)sj[t]*DIN + d0 + dd];
    }
    __syncthreads();
    #pragma unroll
    for (int i = 0; i < 16; i++) {
      int d = tq*16 + i;
      ob[(size_t)(d0+d)*TT + t0 + dd] = tile[dd][d] + out_b[d0+d];
    }
    __syncthreads();
  }
}

// ---------------- launch ----------------
extern "C" void kernel_launch(void* const* d_in, const int* in_sizes, int n_in,
                              void* d_out, int out_size, void* d_ws, size_t ws_size,
                              hipStream_t stream) {
  const float* z        = (const float*)d_in[0];
  const float* in_v     = (const float*)d_in[1];
  const float* in_g     = (const float*)d_in[2];
  const float* in_b     = (const float*)d_in[3];
  const float* out_v    = (const float*)d_in[4];
  const float* out_g    = (const float*)d_in[5];
  const float* out_b    = (const float*)d_in[6];
  const float* codebook = (const float*)d_in[7];

  char* w = (char*)d_ws;
  float* w_in   = (float*)(w + OFF_WIN);
  float* w_outT = (float*)(w + OFF_WOUTT);
  float* cbn    = (float*)(w + OFF_CBN);
  float* nrm2   = (float*)(w + OFF_NRM2);
  float* z_e    = (float*)(w + OFF_ZE);
  float* inv    = (float*)(w + OFF_INV);
  float* enc2   = (float*)(w + OFF_ENC2);
  unsigned long long* keys = (unsigned long long*)(w + OFF_KEYS);
  float* loss_sums = (float*)(w + OFF_LOSS);
  float* W2T    = (float*)(w + OFF_W2T);

  float* out      = (float*)d_out;
  float* out_loss = out + (size_t)BB*DIN*TT;       // 33,554,432
  float* out_idx  = out_loss + 16;

  hipMemsetAsync(keys, 0xFF, 32768ull*8, stream);
  hipMemsetAsync(loss_sums, 0, 32, stream);

  k_prep_win <<<256, 256, 0, stream>>>(in_v, in_g, w_in);
  k_prep_wout<<<1024, 256, 0, stream>>>(out_v, out_g, w_outT);
  k_prep_cb  <<<8192, 256, 0, stream>>>(codebook, cbn, nrm2);

  // z_e[b] = w_in (256x1024) @ z[b] (1024x4096) + in_b
  k_gemm<true><<<dim3(32, 2, 8), 256, 0, stream>>>(
      w_in, z, in_b, z_e, 1024, 1024, 4096, 4096,
      (size_t)DIN*TT, (size_t)DC*TT);

  // W2T[j][d] = codebook (8192x256) @ w_outT (256x1024)
  k_gemm<false><<<dim3(8, 64, 1), 256, 0, stream>>>(
      codebook, w_outT, nullptr, W2T, 256, 256, 1024, 1024,
      (size_t)0, (size_t)0);

  k_colnorm<<<128, 256, 0, stream>>>(z_e, inv, enc2);

  k_dist<<<dim3(64, 32, 8), 256, 0, stream>>>(z_e, cbn, nrm2, inv, enc2, keys);

  k_lossidx<<<dim3(64, 8), 256, 0, stream>>>(z_e, codebook, keys, loss_sums, out_idx);
  k_losswrite<<<1, 64, 0, stream>>>(loss_sums, out_loss);
  k_outgather<<<dim3(64, 8), 256, 0, stream>>>(W2T, keys, out_b, out);
}

// Round 2
// 1077.705 us; speedup vs baseline: 1.8555x; 1.8555x over previous
//
#include <hip/hip_runtime.h>
#include <stdint.h>

#define BB 8
#define TT 4096
#define DIN 1024
#define DC 256
#define CS 8192
#define EPSF 1e-12f

typedef unsigned short ushort_t;
typedef __attribute__((ext_vector_type(8))) short short8;
typedef __attribute__((ext_vector_type(4))) float f32x4;

// ---------------- workspace layout (bytes) ----------------
constexpr size_t OFF_WIN   = 0;                          // w_in:   256*1024 f
constexpr size_t OFF_WOUTT = OFF_WIN   + 262144ull*4;    // w_outT: 256*1024 f  [c][d]
constexpr size_t OFF_CBN   = OFF_WOUTT + 262144ull*4;    // cb_hi/cb_lo: 2 * 8192*256 ushort (8.39MB, = old fp32 cbn slot)
constexpr size_t OFF_NRM2  = OFF_CBN   + 2097152ull*4;   // nrm2:   8192 f
constexpr size_t OFF_ZE    = OFF_NRM2  + 8192ull*4;      // z_e:    8*256*4096 f  [b][c][t]
constexpr size_t OFF_INV   = OFF_ZE    + 8388608ull*4;   // inv:    32768 f
constexpr size_t OFF_ENC2  = OFF_INV   + 32768ull*4;     // enc2:   32768 f
constexpr size_t OFF_KEYS  = OFF_ENC2  + 32768ull*4;     // keys:   32768 u64
constexpr size_t OFF_LOSS  = OFF_KEYS  + 32768ull*8;     // loss:   8 f (+pad)
constexpr size_t OFF_W2T   = OFF_LOSS  + 256;            // enc_hi/enc_lo (2*16.78MB) THEN (after k_dist) W2T: 8192*1024 f

// ---------------- helpers ----------------
__device__ __forceinline__ float block_reduce_sum_256(float v, float* sbuf) {
  #pragma unroll
  for (int o = 32; o > 0; o >>= 1) v += __shfl_down(v, o, 64);
  int lane = threadIdx.x & 63, w = threadIdx.x >> 6;
  if (lane == 0) sbuf[w] = v;
  __syncthreads();
  float r = sbuf[0] + sbuf[1] + sbuf[2] + sbuf[3];
  __syncthreads();
  return r;
}

__device__ __forceinline__ ushort_t bf16_rne(float x) {
  unsigned u = __float_as_uint(x);
  unsigned r = (u + 0x7FFFu + ((u >> 16) & 1u)) >> 16;
  return (ushort_t)r;
}
__device__ __forceinline__ float bf16f(ushort_t h) {
  return __uint_as_float(((unsigned)h) << 16);
}

__device__ __forceinline__ void async_copy16(const ushort_t* g, ushort_t* lds) {
  __builtin_amdgcn_global_load_lds(
      (const __attribute__((address_space(1))) void*)g,
      (__attribute__((address_space(3))) void*)lds, 16, 0, 0);
}

// ---------------- weight prep ----------------
__global__ void k_prep_win(const float* __restrict__ v, const float* __restrict__ g,
                           float* __restrict__ w) {
  __shared__ float sb[4];
  int r = blockIdx.x, t = threadIdx.x;
  float xv[4]; float s = 0.f;
  #pragma unroll
  for (int i = 0; i < 4; i++) { xv[i] = v[r*DIN + t + i*256]; s += xv[i]*xv[i]; }
  s = block_reduce_sum_256(s, sb);
  float sc = g[r] / fmaxf(sqrtf(s), EPSF);
  #pragma unroll
  for (int i = 0; i < 4; i++) w[r*DIN + t + i*256] = xv[i] * sc;
}

__global__ void k_prep_wout(const float* __restrict__ v, const float* __restrict__ g,
                            float* __restrict__ wT) {
  __shared__ float sb[4];
  int r = blockIdx.x, t = threadIdx.x;      // r in [0,1024), t in [0,256)
  float x = v[r*DC + t];
  float s = block_reduce_sum_256(x*x, sb);
  float sc = g[r] / fmaxf(sqrtf(s), EPSF);
  wT[t*DIN + r] = x * sc;
}

__global__ void k_prep_cb(const float* __restrict__ cb, ushort_t* __restrict__ cbh,
                          ushort_t* __restrict__ cbl, float* __restrict__ nrm2) {
  __shared__ float sb[4];
  int j = blockIdx.x, t = threadIdx.x;      // j in [0,8192), t in [0,256)
  float x = cb[j*DC + t];
  float s = block_reduce_sum_256(x*x, sb);
  float nm = fmaxf(sqrtf(s), EPSF);
  float cn = x / nm;                        // match reference: divide
  ushort_t h = bf16_rne(cn);
  cbh[j*DC + t] = h;
  cbl[j*DC + t] = bf16_rne(cn - bf16f(h));
  float q = block_reduce_sum_256(cn*cn, sb);
  if (t == 0) nrm2[j] = q;
}

// ---------------- generic fp32 GEMM: C[m][n] = sum_k A[m][k]*B[k][n] (+bias[m]) ----------------
template<bool BIAS>
__global__ __launch_bounds__(256) void k_gemm(
    const float* __restrict__ A, const float* __restrict__ Bmat,
    const float* __restrict__ bias, float* __restrict__ C,
    int K, int lda, int ldb, int ldc, size_t strideB, size_t strideC)
{
  __shared__ float As[16][132];
  __shared__ float Bs[16][132];
  const int bn = blockIdx.x * 128;
  const int bm = blockIdx.y * 128;
  const float* Bb = Bmat + (size_t)blockIdx.z * strideB;
  float* Cb = C + (size_t)blockIdx.z * strideC;
  const int tid = threadIdx.x;
  const int tx = tid & 15, ty = tid >> 4;
  const int am = tid & 127, akq = (tid >> 7) * 8;
  const int bk = tid >> 5, bj = (tid & 31) * 4;

  float acc[8][8];
  #pragma unroll
  for (int i = 0; i < 8; i++)
    #pragma unroll
    for (int j = 0; j < 8; j++) acc[i][j] = 0.f;

  for (int k0 = 0; k0 < K; k0 += 16) {
    float4 a0 = *(const float4*)&A[(size_t)(bm+am)*lda + k0 + akq];
    float4 a1 = *(const float4*)&A[(size_t)(bm+am)*lda + k0 + akq + 4];
    float4 b0 = *(const float4*)&Bb[(size_t)(k0+bk)*ldb + bn + bj];
    float4 b1 = *(const float4*)&Bb[(size_t)(k0+bk+8)*ldb + bn + bj];
    As[akq+0][am] = a0.x; As[akq+1][am] = a0.y; As[akq+2][am] = a0.z; As[akq+3][am] = a0.w;
    As[akq+4][am] = a1.x; As[akq+5][am] = a1.y; As[akq+6][am] = a1.z; As[akq+7][am] = a1.w;
    *(float4*)&Bs[bk][bj] = b0;
    *(float4*)&Bs[bk+8][bj] = b1;
    __syncthreads();
    #pragma unroll
    for (int k = 0; k < 16; k++) {
      float av[8], bv[8];
      float4 x0 = *(const float4*)&As[k][tx*4];
      float4 x1 = *(const float4*)&As[k][tx*4+64];
      float4 y0 = *(const float4*)&Bs[k][ty*4];
      float4 y1 = *(const float4*)&Bs[k][ty*4+64];
      av[0]=x0.x; av[1]=x0.y; av[2]=x0.z; av[3]=x0.w;
      av[4]=x1.x; av[5]=x1.y; av[6]=x1.z; av[7]=x1.w;
      bv[0]=y0.x; bv[1]=y0.y; bv[2]=y0.z; bv[3]=y0.w;
      bv[4]=y1.x; bv[5]=y1.y; bv[6]=y1.z; bv[7]=y1.w;
      #pragma unroll
      for (int i = 0; i < 8; i++)
        #pragma unroll
        for (int j = 0; j < 8; j++)
          acc[i][j] += av[i] * bv[j];
    }
    __syncthreads();
  }

  #pragma unroll
  for (int i = 0; i < 8; i++) {
    int m = bm + ((i < 4) ? tx*4 + i : 64 + tx*4 + (i-4));
    float bia = BIAS ? bias[m] : 0.f;
    float4 v0 = make_float4(acc[i][0]+bia, acc[i][1]+bia, acc[i][2]+bia, acc[i][3]+bia);
    float4 v1 = make_float4(acc[i][4]+bia, acc[i][5]+bia, acc[i][6]+bia, acc[i][7]+bia);
    *(float4*)&Cb[(size_t)m*ldc + bn + ty*4]      = v0;
    *(float4*)&Cb[(size_t)m*ldc + bn + 64 + ty*4] = v1;
  }
}

// ---------------- column norms of z_e ----------------
__global__ void k_colnorm(const float* __restrict__ ze, float* __restrict__ inv,
                          float* __restrict__ enc2) {
  int r = blockIdx.x * 256 + threadIdx.x;        // [0, 32768)
  int b = r >> 12, t = r & 4095;
  const float* p = ze + (size_t)b*DC*TT + t;
  float s = 0.f;
  for (int c = 0; c < DC; c++) { float x = p[(size_t)c*TT]; s += x*x; }
  float iv = 1.f / fmaxf(sqrtf(s), EPSF);
  inv[r] = iv;
  enc2[r] = (s * iv) * iv;
}

// ---------------- normalize + transpose + bf16-split: enc[b][t][c] hi/lo ----------------
__global__ void k_split_enc(const float* __restrict__ ze, const float* __restrict__ inv,
                            ushort_t* __restrict__ ehi, ushort_t* __restrict__ elo) {
  __shared__ float tile[64][65];
  int b = blockIdx.z, t0 = blockIdx.x * 64, c0 = blockIdx.y * 64;
  int tx = threadIdx.x & 63, ty = threadIdx.x >> 6;
  const float* zb = ze + (size_t)b*DC*TT;
  #pragma unroll
  for (int i = 0; i < 16; i++) {
    int c = i*4 + ty;
    tile[c][tx] = zb[(size_t)(c0+c)*TT + t0 + tx];
  }
  __syncthreads();
  #pragma unroll
  for (int i = 0; i < 16; i++) {
    int t = i*4 + ty;
    float iv = inv[b*TT + t0 + t];
    float val = tile[tx][t] * iv;
    ushort_t h = bf16_rne(val);
    size_t o = ((size_t)(b*TT + t0 + t))*DC + c0 + tx;
    ehi[o] = h;
    elo[o] = bf16_rne(val - bf16f(h));
  }
}

// ---------------- fused distance + argmin (split-bf16 MFMA) ----------------
// grid: (CS/128, TT/128, B); block 256 = 4 waves (2x2); tile 128x128, BK=32
__global__ __launch_bounds__(256) void k_dist_mfma(
    const ushort_t* __restrict__ ehi, const ushort_t* __restrict__ elo,
    const ushort_t* __restrict__ cbh, const ushort_t* __restrict__ cbl,
    const float* __restrict__ nrm2, const float* __restrict__ enc2,
    unsigned long long* __restrict__ keys)
{
  __shared__ ushort_t As_hi[128*32];
  __shared__ ushort_t As_lo[128*32];
  __shared__ ushort_t Bs_hi[128*32];
  __shared__ ushort_t Bs_lo[128*32];
  __shared__ float sE2[128];
  __shared__ float sN2[128];
  __shared__ unsigned long long rkey[128];

  const int b  = blockIdx.z;
  const int t0 = blockIdx.y * 128;
  const int j0 = blockIdx.x * 128;
  const int tid = threadIdx.x;
  const int lane = tid & 63;
  const int wave = tid >> 6;
  const int wr = wave >> 1, wc = wave & 1;
  const int m = lane & 15, quad = lane >> 4;

  if (tid < 128) {
    sE2[tid] = enc2[b*TT + t0 + tid];
    sN2[tid] = nrm2[j0 + tid];
    rkey[tid] = 0xFFFFFFFFFFFFFFFFull;
  }

  // per-wave staging source/dest (one 8KB buffer each)
  const ushort_t* src;
  ushort_t* dst;
  {
    size_t aoff = ((size_t)(b*TT + t0)) * DC;
    size_t boff = ((size_t)j0) * DC;
    if      (wave == 0) { src = ehi + aoff; dst = As_hi; }
    else if (wave == 1) { src = elo + aoff; dst = As_lo; }
    else if (wave == 2) { src = cbh + boff; dst = Bs_hi; }
    else                { src = cbl + boff; dst = Bs_lo; }
  }
  const int rr = lane >> 2;          // 0..15  (row within 16-row group)
  const int cc = lane & 3;           // chunk slot

  // fragment byte-offsets within an 8KB buffer (k-independent, swizzled)
  int offA[4], offB[4];
  #pragma unroll
  for (int ri = 0; ri < 4; ri++) {
    int r = wr*64 + ri*16 + m;
    int p = quad ^ ((r + (r >> 2)) & 3);
    offA[ri] = r*64 + p*16;
  }
  #pragma unroll
  for (int ci = 0; ci < 4; ci++) {
    int r = wc*64 + ci*16 + m;
    int p = quad ^ ((r + (r >> 2)) & 3);
    offB[ci] = r*64 + p*16;
  }

  f32x4 acc[4][4];
  #pragma unroll
  for (int i = 0; i < 4; i++)
    #pragma unroll
    for (int j = 0; j < 4; j++) acc[i][j] = (f32x4)0.f;

  for (int k0 = 0; k0 < DC; k0 += 32) {
    __syncthreads();                 // previous tile consumed (also covers init)
    const ushort_t* s0 = src + k0;
    #pragma unroll
    for (int r16 = 0; r16 < 8; r16++) {
      int r = r16*16 + rr;
      int g = cc ^ ((r + (r >> 2)) & 3);
      async_copy16(s0 + (size_t)r*DC + g*8, dst + r16*512);
    }
    __syncthreads();                 // staging complete

    short8 bh[4], bl[4];
    #pragma unroll
    for (int ci = 0; ci < 4; ci++) {
      bh[ci] = *(const short8*)((const char*)Bs_hi + offB[ci]);
      bl[ci] = *(const short8*)((const char*)Bs_lo + offB[ci]);
    }
    #pragma unroll
    for (int ri = 0; ri < 4; ri++) {
      short8 ah = *(const short8*)((const char*)As_hi + offA[ri]);
      short8 al = *(const short8*)((const char*)As_lo + offA[ri]);
      #pragma unroll
      for (int ci = 0; ci < 4; ci++) {
        acc[ri][ci] = __builtin_amdgcn_mfma_f32_16x16x32_bf16(ah, bh[ci], acc[ri][ci], 0, 0, 0);
        acc[ri][ci] = __builtin_amdgcn_mfma_f32_16x16x32_bf16(al, bh[ci], acc[ri][ci], 0, 0, 0);
        acc[ri][ci] = __builtin_amdgcn_mfma_f32_16x16x32_bf16(ah, bl[ci], acc[ri][ci], 0, 0, 0);
      }
    }
  }

  // epilogue: d = (e2 - 2*dot) + nrm2, argmin via packed (dist,idx) keys
  #pragma unroll
  for (int ri = 0; ri < 4; ri++) {
    #pragma unroll
    for (int reg = 0; reg < 4; reg++) {
      int r_loc = wr*64 + ri*16 + quad*4 + reg;
      float e2 = sE2[r_loc];
      unsigned long long best = 0xFFFFFFFFFFFFFFFFull;
      #pragma unroll
      for (int ci = 0; ci < 4; ci++) {
        int j_loc = wc*64 + ci*16 + m;
        float d = e2 - 2.0f * acc[ri][ci][reg];
        d = d + sN2[j_loc];
        unsigned long long key =
            ((unsigned long long)__float_as_uint(d) << 32) | (unsigned)(j0 + j_loc);
        best = key < best ? key : best;
      }
      #pragma unroll
      for (int off = 1; off < 16; off <<= 1) {
        unsigned long long o = __shfl_xor(best, off);
        best = o < best ? o : best;
      }
      if (m == 0) atomicMin(&rkey[r_loc], best);
    }
  }
  __syncthreads();
  if (tid < 128) atomicMin(&keys[(size_t)b*TT + t0 + tid], rkey[tid]);
}

// ---------------- losses + indices ----------------
__global__ void k_lossidx(const float* __restrict__ ze, const float* __restrict__ cb,
                          const unsigned long long* __restrict__ keys,
                          float* __restrict__ loss_sums, float* __restrict__ out_idx)
{
  __shared__ float sb[4];
  __shared__ int sj[64];
  int b = blockIdx.y, t0 = blockIdx.x * 64;
  int tid = threadIdx.x;
  if (tid < 64) {
    unsigned long long k = keys[(size_t)b*TT + t0 + tid];
    int j = (int)(unsigned)(k & 0xFFFFFFFFull);
    sj[tid] = j;
    out_idx[(size_t)b*TT + t0 + tid] = (float)j;
  }
  __syncthreads();
  int tt = tid & 63, tc = tid >> 6;
  const float* zb = ze + (size_t)b*DC*TT + t0;
  int j = sj[tt];
  float s = 0.f;
  for (int ci = 0; ci < 64; ci++) {
    int c = tc + ci*4;
    float zev = zb[(size_t)c*TT + tt];
    float zqv = cb[(size_t)j*DC + c];
    float d = zev - zqv;
    s += d*d;
  }
  s = block_reduce_sum_256(s, sb);
  if (tid == 0) atomicAdd(&loss_sums[b], s);
}

__global__ void k_losswrite(const float* __restrict__ loss_sums, float* __restrict__ out_loss) {
  int i = threadIdx.x;
  if (i < 8) {
    float v = loss_sums[i] * (1.f/1048576.f);
    out_loss[i] = v;
    out_loss[8 + i] = v;
  }
}

// ---------------- output gather ----------------
__global__ void k_outgather(const float* __restrict__ W2T,
                            const unsigned long long* __restrict__ keys,
                            const float* __restrict__ out_b, float* __restrict__ out)
{
  __shared__ float tile[64][65];
  __shared__ int sj[64];
  int b = blockIdx.y, t0 = blockIdx.x * 64;
  int tid = threadIdx.x;
  if (tid < 64) sj[tid] = (int)(unsigned)(keys[(size_t)b*TT + t0 + tid] & 0xFFFFFFFFull);
  __syncthreads();
  float* ob = out + (size_t)b*DIN*TT;
  int dd = tid & 63, tq = tid >> 6;
  for (int d0 = 0; d0 < DIN; d0 += 64) {
    #pragma unroll
    for (int i = 0; i < 16; i++) {
      int t = tq*16 + i;
      tile[t][dd] = W2T[(size_t)sj[t]*DIN + d0 + dd];
    }
    __syncthreads();
    #pragma unroll
    for (int i = 0; i < 16; i++) {
      int d = tq*16 + i;
      ob[(size_t)(d0+d)*TT + t0 + dd] = tile[dd][d] + out_b[d0+d];
    }
    __syncthreads();
  }
}

// ---------------- launch ----------------
extern "C" void kernel_launch(void* const* d_in, const int* in_sizes, int n_in,
                              void* d_out, int out_size, void* d_ws, size_t ws_size,
                              hipStream_t stream) {
  const float* z        = (const float*)d_in[0];
  const float* in_v     = (const float*)d_in[1];
  const float* in_g     = (const float*)d_in[2];
  const float* in_b     = (const float*)d_in[3];
  const float* out_v    = (const float*)d_in[4];
  const float* out_g    = (const float*)d_in[5];
  const float* out_b    = (const float*)d_in[6];
  const float* codebook = (const float*)d_in[7];

  char* w = (char*)d_ws;
  float* w_in   = (float*)(w + OFF_WIN);
  float* w_outT = (float*)(w + OFF_WOUTT);
  ushort_t* cb_hi = (ushort_t*)(w + OFF_CBN);
  ushort_t* cb_lo = cb_hi + (size_t)CS*DC;
  float* nrm2   = (float*)(w + OFF_NRM2);
  float* z_e    = (float*)(w + OFF_ZE);
  float* inv    = (float*)(w + OFF_INV);
  float* enc2   = (float*)(w + OFF_ENC2);
  unsigned long long* keys = (unsigned long long*)(w + OFF_KEYS);
  float* loss_sums = (float*)(w + OFF_LOSS);
  // enc_hi/enc_lo alias the W2T slot; W2T GEMM runs AFTER k_dist_mfma.
  ushort_t* enc_hi = (ushort_t*)(w + OFF_W2T);
  ushort_t* enc_lo = enc_hi + (size_t)BB*TT*DC;
  float* W2T    = (float*)(w + OFF_W2T);

  float* out      = (float*)d_out;
  float* out_loss = out + (size_t)BB*DIN*TT;
  float* out_idx  = out_loss + 16;

  hipMemsetAsync(keys, 0xFF, 32768ull*8, stream);
  hipMemsetAsync(loss_sums, 0, 32, stream);

  k_prep_win <<<256, 256, 0, stream>>>(in_v, in_g, w_in);
  k_prep_wout<<<1024, 256, 0, stream>>>(out_v, out_g, w_outT);
  k_prep_cb  <<<8192, 256, 0, stream>>>(codebook, cb_hi, cb_lo, nrm2);

  // z_e[b] = w_in (256x1024) @ z[b] (1024x4096) + in_b
  k_gemm<true><<<dim3(32, 2, 8), 256, 0, stream>>>(
      w_in, z, in_b, z_e, 1024, 1024, 4096, 4096,
      (size_t)DIN*TT, (size_t)DC*TT);

  k_colnorm<<<128, 256, 0, stream>>>(z_e, inv, enc2);
  k_split_enc<<<dim3(64, 4, 8), 256, 0, stream>>>(z_e, inv, enc_hi, enc_lo);

  k_dist_mfma<<<dim3(64, 32, 8), 256, 0, stream>>>(
      enc_hi, enc_lo, cb_hi, cb_lo, nrm2, enc2, keys);

  // W2T[j][d] = codebook (8192x256) @ w_outT (256x1024)  — overwrites enc_hi/lo
  k_gemm<false><<<dim3(8, 64, 1), 256, 0, stream>>>(
      codebook, w_outT, nullptr, W2T, 256, 256, 1024, 1024,
      (size_t)0, (size_t)0);

  k_lossidx<<<dim3(64, 8), 256, 0, stream>>>(z_e, codebook, keys, loss_sums, out_idx);
  k_losswrite<<<1, 64, 0, stream>>>(loss_sums, out_loss);
  k_outgather<<<dim3(64, 8), 256, 0, stream>>>(W2T, keys, out_b, out);
}

// Round 3
// 977.522 us; speedup vs baseline: 2.0456x; 1.1025x over previous
//
#include <hip/hip_runtime.h>
#include <stdint.h>

#define BB 8
#define TT 4096
#define DIN 1024
#define DC 256
#define CS 8192
#define EPSF 1e-12f

typedef unsigned short ushort_t;
typedef __attribute__((ext_vector_type(8))) short short8;
typedef __attribute__((ext_vector_type(4))) float f32x4;

// ---------------- workspace layout (bytes) ----------------
constexpr size_t OFF_WIN   = 0;                          // w_in fp32: 1MB
constexpr size_t OFF_WOUTT = OFF_WIN   + 1048576;        // w_outT fp32: 1MB
constexpr size_t OFF_CBN   = OFF_WOUTT + 1048576;        // cb_hi/cb_lo bf16: 8.39MB
constexpr size_t OFF_NRM2  = OFF_CBN   + 8388608;        // nrm2: 32KB
constexpr size_t OFF_ZE    = OFF_NRM2  + 32768;          // z_e fp32: 33.55MB
constexpr size_t OFF_INV   = OFF_ZE    + 33554432;       // inv: 128KB
constexpr size_t OFF_ENC2  = OFF_INV   + 131072;         // enc2: 128KB
constexpr size_t OFF_KEYS  = OFF_ENC2  + 131072;         // keys u64: 256KB
constexpr size_t OFF_LOSS  = OFF_KEYS  + 262144;         // loss: 256B
constexpr size_t OFF_WSPL  = OFF_LOSS  + 256;            // w_hi/w_lo bf16: 1MB
constexpr size_t OFF_W2T   = OFF_WSPL  + 1048576;        // zT(134MB) -> enc(33.6MB) -> W2T(33.6MB)
constexpr size_t REQ_WS_ZE = OFF_W2T + 134217728ull;     // ~180MB: needed for MFMA z_e path

// ---------------- helpers ----------------
__device__ __forceinline__ float block_reduce_sum_256(float v, float* sbuf) {
  #pragma unroll
  for (int o = 32; o > 0; o >>= 1) v += __shfl_down(v, o, 64);
  int lane = threadIdx.x & 63, w = threadIdx.x >> 6;
  if (lane == 0) sbuf[w] = v;
  __syncthreads();
  float r = sbuf[0] + sbuf[1] + sbuf[2] + sbuf[3];
  __syncthreads();
  return r;
}

__device__ __forceinline__ ushort_t bf16_rne(float x) {
  unsigned u = __float_as_uint(x);
  unsigned r = (u + 0x7FFFu + ((u >> 16) & 1u)) >> 16;
  return (ushort_t)r;
}
__device__ __forceinline__ float bf16f(ushort_t h) {
  return __uint_as_float(((unsigned)h) << 16);
}

__device__ __forceinline__ void async_copy16(const ushort_t* g, ushort_t* lds) {
  __builtin_amdgcn_global_load_lds(
      (const __attribute__((address_space(1))) void*)g,
      (__attribute__((address_space(3))) void*)lds, 16, 0, 0);
}

// stage one 128x32 bf16 tile (8KB) into LDS with XOR-swizzle; per-wave.
// ld = global row stride (elements). dstbuf = wave-uniform LDS base.
__device__ __forceinline__ void stage_tile(const ushort_t* __restrict__ s0, int ld,
                                           ushort_t* __restrict__ dstbuf, int rr, int cc) {
  #pragma unroll
  for (int r16 = 0; r16 < 8; r16++) {
    int r = r16*16 + rr;
    int g = cc ^ ((r + (r >> 2)) & 3);
    async_copy16(s0 + (size_t)r*ld + (g << 3), dstbuf + r16*512);
  }
}

// ---------------- weight prep ----------------
__global__ void k_prep_win(const float* __restrict__ v, const float* __restrict__ g,
                           float* __restrict__ w, ushort_t* __restrict__ wh,
                           ushort_t* __restrict__ wl) {
  __shared__ float sb[4];
  int r = blockIdx.x, t = threadIdx.x;
  float xv[4]; float s = 0.f;
  #pragma unroll
  for (int i = 0; i < 4; i++) { xv[i] = v[r*DIN + t + i*256]; s += xv[i]*xv[i]; }
  s = block_reduce_sum_256(s, sb);
  float sc = g[r] / fmaxf(sqrtf(s), EPSF);
  #pragma unroll
  for (int i = 0; i < 4; i++) {
    float val = xv[i] * sc;
    int idx = r*DIN + t + i*256;
    w[idx] = val;
    ushort_t h = bf16_rne(val);
    wh[idx] = h;
    wl[idx] = bf16_rne(val - bf16f(h));
  }
}

__global__ void k_prep_wout(const float* __restrict__ v, const float* __restrict__ g,
                            float* __restrict__ wT) {
  __shared__ float sb[4];
  int r = blockIdx.x, t = threadIdx.x;
  float x = v[r*DC + t];
  float s = block_reduce_sum_256(x*x, sb);
  float sc = g[r] / fmaxf(sqrtf(s), EPSF);
  wT[t*DIN + r] = x * sc;
}

__global__ void k_prep_cb(const float* __restrict__ cb, ushort_t* __restrict__ cbh,
                          ushort_t* __restrict__ cbl, float* __restrict__ nrm2) {
  __shared__ float sb[4];
  int j = blockIdx.x, t = threadIdx.x;
  float x = cb[j*DC + t];
  float s = block_reduce_sum_256(x*x, sb);
  float nm = fmaxf(sqrtf(s), EPSF);
  float cn = x / nm;
  ushort_t h = bf16_rne(cn);
  cbh[j*DC + t] = h;
  cbl[j*DC + t] = bf16_rne(cn - bf16f(h));
  float q = block_reduce_sum_256(cn*cn, sb);
  if (t == 0) nrm2[j] = q;
}

// ---------------- fp32 GEMM (fallback for z_e; always used for W2T) ----------------
template<bool BIAS>
__global__ __launch_bounds__(256) void k_gemm(
    const float* __restrict__ A, const float* __restrict__ Bmat,
    const float* __restrict__ bias, float* __restrict__ C,
    int K, int lda, int ldb, int ldc, size_t strideB, size_t strideC)
{
  __shared__ float As[16][132];
  __shared__ float Bs[16][132];
  const int bn = blockIdx.x * 128;
  const int bm = blockIdx.y * 128;
  const float* Bb = Bmat + (size_t)blockIdx.z * strideB;
  float* Cb = C + (size_t)blockIdx.z * strideC;
  const int tid = threadIdx.x;
  const int tx = tid & 15, ty = tid >> 4;
  const int am = tid & 127, akq = (tid >> 7) * 8;
  const int bk = tid >> 5, bj = (tid & 31) * 4;

  float acc[8][8];
  #pragma unroll
  for (int i = 0; i < 8; i++)
    #pragma unroll
    for (int j = 0; j < 8; j++) acc[i][j] = 0.f;

  for (int k0 = 0; k0 < K; k0 += 16) {
    float4 a0 = *(const float4*)&A[(size_t)(bm+am)*lda + k0 + akq];
    float4 a1 = *(const float4*)&A[(size_t)(bm+am)*lda + k0 + akq + 4];
    float4 b0 = *(const float4*)&Bb[(size_t)(k0+bk)*ldb + bn + bj];
    float4 b1 = *(const float4*)&Bb[(size_t)(k0+bk+8)*ldb + bn + bj];
    As[akq+0][am] = a0.x; As[akq+1][am] = a0.y; As[akq+2][am] = a0.z; As[akq+3][am] = a0.w;
    As[akq+4][am] = a1.x; As[akq+5][am] = a1.y; As[akq+6][am] = a1.z; As[akq+7][am] = a1.w;
    *(float4*)&Bs[bk][bj] = b0;
    *(float4*)&Bs[bk+8][bj] = b1;
    __syncthreads();
    #pragma unroll
    for (int k = 0; k < 16; k++) {
      float av[8], bv[8];
      float4 x0 = *(const float4*)&As[k][tx*4];
      float4 x1 = *(const float4*)&As[k][tx*4+64];
      float4 y0 = *(const float4*)&Bs[k][ty*4];
      float4 y1 = *(const float4*)&Bs[k][ty*4+64];
      av[0]=x0.x; av[1]=x0.y; av[2]=x0.z; av[3]=x0.w;
      av[4]=x1.x; av[5]=x1.y; av[6]=x1.z; av[7]=x1.w;
      bv[0]=y0.x; bv[1]=y0.y; bv[2]=y0.z; bv[3]=y0.w;
      bv[4]=y1.x; bv[5]=y1.y; bv[6]=y1.z; bv[7]=y1.w;
      #pragma unroll
      for (int i = 0; i < 8; i++)
        #pragma unroll
        for (int j = 0; j < 8; j++)
          acc[i][j] += av[i] * bv[j];
    }
    __syncthreads();
  }

  #pragma unroll
  for (int i = 0; i < 8; i++) {
    int mm = bm + ((i < 4) ? tx*4 + i : 64 + tx*4 + (i-4));
    float bia = BIAS ? bias[mm] : 0.f;
    float4 v0 = make_float4(acc[i][0]+bia, acc[i][1]+bia, acc[i][2]+bia, acc[i][3]+bia);
    float4 v1 = make_float4(acc[i][4]+bia, acc[i][5]+bia, acc[i][6]+bia, acc[i][7]+bia);
    *(float4*)&Cb[(size_t)mm*ldc + bn + ty*4]      = v0;
    *(float4*)&Cb[(size_t)mm*ldc + bn + 64 + ty*4] = v1;
  }
}

// ---------------- split z: [b][d][t] -> zT hi/lo [b][t][d] ----------------
__global__ void k_split_z(const float* __restrict__ z, ushort_t* __restrict__ zhi,
                          ushort_t* __restrict__ zlo) {
  __shared__ float tile[64][65];
  int b = blockIdx.z, t0 = blockIdx.x * 64, d0 = blockIdx.y * 64;
  int tx = threadIdx.x & 63, ty = threadIdx.x >> 6;
  const float* zb = z + (size_t)b*DIN*TT;
  #pragma unroll
  for (int i = 0; i < 16; i++) {
    int d = i*4 + ty;
    tile[d][tx] = zb[(size_t)(d0+d)*TT + t0 + tx];
  }
  __syncthreads();
  #pragma unroll
  for (int i = 0; i < 16; i++) {
    int t = i*4 + ty;
    float val = tile[tx][t];                 // z[d0+tx][t0+t]
    ushort_t h = bf16_rne(val);
    size_t o = ((size_t)(b*TT + t0 + t))*DIN + d0 + tx;
    zhi[o] = h;
    zlo[o] = bf16_rne(val - bf16f(h));
  }
}

// ---------------- z_e via split-bf16 MFMA, double-buffered ----------------
// grid: (TT/128, DC/128, B); out z_e[b][c][t] fp32, K=DIN=1024
__global__ __launch_bounds__(256) void k_ze_mfma(
    const ushort_t* __restrict__ zth, const ushort_t* __restrict__ ztl,
    const ushort_t* __restrict__ wh, const ushort_t* __restrict__ wl,
    const float* __restrict__ in_b, float* __restrict__ ze)
{
  __shared__ ushort_t As_hi[2][4096];
  __shared__ ushort_t As_lo[2][4096];
  __shared__ ushort_t Bs_hi[2][4096];
  __shared__ ushort_t Bs_lo[2][4096];

  const int b  = blockIdx.z;
  const int t0 = blockIdx.x * 128;
  const int c0 = blockIdx.y * 128;
  const int tid = threadIdx.x;
  const int lane = tid & 63;
  const int wave = tid >> 6;
  const int wr = wave >> 1, wc = wave & 1;
  const int m = lane & 15, quad = lane >> 4;

  const ushort_t* src; ushort_t* dst;
  {
    size_t aoff = ((size_t)(b*TT + t0)) * DIN;
    size_t boff = (size_t)c0 * DIN;
    if      (wave == 0) { src = zth + aoff; dst = &As_hi[0][0]; }
    else if (wave == 1) { src = ztl + aoff; dst = &As_lo[0][0]; }
    else if (wave == 2) { src = wh + boff;  dst = &Bs_hi[0][0]; }
    else                { src = wl + boff;  dst = &Bs_lo[0][0]; }
  }
  const int rr = lane >> 2, cc = lane & 3;

  int offA[4], offB[4];
  #pragma unroll
  for (int ri = 0; ri < 4; ri++) {
    int r = wr*64 + ri*16 + m;
    int p = quad ^ ((r + (r >> 2)) & 3);
    offA[ri] = r*64 + p*16;
  }
  #pragma unroll
  for (int ci = 0; ci < 4; ci++) {
    int r = wc*64 + ci*16 + m;
    int p = quad ^ ((r + (r >> 2)) & 3);
    offB[ci] = r*64 + p*16;
  }

  f32x4 acc[4][4];
  #pragma unroll
  for (int i = 0; i < 4; i++)
    #pragma unroll
    for (int j = 0; j < 4; j++) acc[i][j] = (f32x4)0.f;

  stage_tile(src, DIN, dst, rr, cc);

  for (int it = 0; it < 32; ++it) {
    __syncthreads();                           // drains stage(it) (issued 1 iter ago)
    if (it < 31) stage_tile(src + (it+1)*32, DIN, dst + ((it+1)&1)*4096, rr, cc);
    const int bo = (it & 1) << 13;             // byte offset of current buffer

    short8 bh[4], bl[4];
    #pragma unroll
    for (int ci = 0; ci < 4; ci++) {
      bh[ci] = *(const short8*)((const char*)Bs_hi + bo + offB[ci]);
      bl[ci] = *(const short8*)((const char*)Bs_lo + bo + offB[ci]);
    }
    #pragma unroll
    for (int ri = 0; ri < 4; ri++) {
      short8 ah = *(const short8*)((const char*)As_hi + bo + offA[ri]);
      short8 al = *(const short8*)((const char*)As_lo + bo + offA[ri]);
      #pragma unroll
      for (int ci = 0; ci < 4; ci++) {
        acc[ri][ci] = __builtin_amdgcn_mfma_f32_16x16x32_bf16(ah, bh[ci], acc[ri][ci], 0, 0, 0);
        acc[ri][ci] = __builtin_amdgcn_mfma_f32_16x16x32_bf16(al, bh[ci], acc[ri][ci], 0, 0, 0);
        acc[ri][ci] = __builtin_amdgcn_mfma_f32_16x16x32_bf16(ah, bl[ci], acc[ri][ci], 0, 0, 0);
      }
    }
  }

  // store: C[m=t][n=c] -> z_e[b][c0+c][t0+t] (+bias), 4 consecutive t per lane
  #pragma unroll
  for (int ri = 0; ri < 4; ri++) {
    int t_loc = wr*64 + ri*16 + quad*4;
    #pragma unroll
    for (int ci = 0; ci < 4; ci++) {
      int c_loc = wc*64 + ci*16 + m;
      float bia = in_b[c0 + c_loc];
      float4 v = make_float4(acc[ri][ci][0]+bia, acc[ri][ci][1]+bia,
                             acc[ri][ci][2]+bia, acc[ri][ci][3]+bia);
      *(float4*)&ze[((size_t)b*DC + c0 + c_loc)*TT + t0 + t_loc] = v;
    }
  }
}

// ---------------- column norms of z_e ----------------
__global__ void k_colnorm(const float* __restrict__ ze, float* __restrict__ inv,
                          float* __restrict__ enc2) {
  int r = blockIdx.x * 256 + threadIdx.x;
  int b = r >> 12, t = r & 4095;
  const float* p = ze + (size_t)b*DC*TT + t;
  float s = 0.f;
  for (int c = 0; c < DC; c++) { float x = p[(size_t)c*TT]; s += x*x; }
  float iv = 1.f / fmaxf(sqrtf(s), EPSF);
  inv[r] = iv;
  enc2[r] = (s * iv) * iv;
}

// ---------------- normalize + transpose + bf16-split enc ----------------
__global__ void k_split_enc(const float* __restrict__ ze, const float* __restrict__ inv,
                            ushort_t* __restrict__ ehi, ushort_t* __restrict__ elo) {
  __shared__ float tile[64][65];
  int b = blockIdx.z, t0 = blockIdx.x * 64, c0 = blockIdx.y * 64;
  int tx = threadIdx.x & 63, ty = threadIdx.x >> 6;
  const float* zb = ze + (size_t)b*DC*TT;
  #pragma unroll
  for (int i = 0; i < 16; i++) {
    int c = i*4 + ty;
    tile[c][tx] = zb[(size_t)(c0+c)*TT + t0 + tx];
  }
  __syncthreads();
  #pragma unroll
  for (int i = 0; i < 16; i++) {
    int t = i*4 + ty;
    float iv = inv[b*TT + t0 + t];
    float val = tile[tx][t] * iv;
    ushort_t h = bf16_rne(val);
    size_t o = ((size_t)(b*TT + t0 + t))*DC + c0 + tx;
    ehi[o] = h;
    elo[o] = bf16_rne(val - bf16f(h));
  }
}

// ---------------- fused distance + argmin (split-bf16 MFMA, double-buffered) ----------------
__global__ __launch_bounds__(256) void k_dist_mfma(
    const ushort_t* __restrict__ ehi, const ushort_t* __restrict__ elo,
    const ushort_t* __restrict__ cbh, const ushort_t* __restrict__ cbl,
    const float* __restrict__ nrm2, const float* __restrict__ enc2,
    unsigned long long* __restrict__ keys)
{
  __shared__ ushort_t As_hi[2][4096];
  __shared__ ushort_t As_lo[2][4096];
  __shared__ ushort_t Bs_hi[2][4096];
  __shared__ ushort_t Bs_lo[2][4096];
  __shared__ float sE2[128], sN2[128];
  __shared__ unsigned long long rkey[128];

  const int b  = blockIdx.z;
  const int t0 = blockIdx.y * 128;
  const int j0 = blockIdx.x * 128;
  const int tid = threadIdx.x;
  const int lane = tid & 63;
  const int wave = tid >> 6;
  const int wr = wave >> 1, wc = wave & 1;
  const int m = lane & 15, quad = lane >> 4;

  if (tid < 128) {
    sE2[tid] = enc2[b*TT + t0 + tid];
    sN2[tid] = nrm2[j0 + tid];
    rkey[tid] = 0xFFFFFFFFFFFFFFFFull;
  }

  const ushort_t* src; ushort_t* dst;
  {
    size_t aoff = ((size_t)(b*TT + t0)) * DC;
    size_t boff = ((size_t)j0) * DC;
    if      (wave == 0) { src = ehi + aoff; dst = &As_hi[0][0]; }
    else if (wave == 1) { src = elo + aoff; dst = &As_lo[0][0]; }
    else if (wave == 2) { src = cbh + boff; dst = &Bs_hi[0][0]; }
    else                { src = cbl + boff; dst = &Bs_lo[0][0]; }
  }
  const int rr = lane >> 2, cc = lane & 3;

  int offA[4], offB[4];
  #pragma unroll
  for (int ri = 0; ri < 4; ri++) {
    int r = wr*64 + ri*16 + m;
    int p = quad ^ ((r + (r >> 2)) & 3);
    offA[ri] = r*64 + p*16;
  }
  #pragma unroll
  for (int ci = 0; ci < 4; ci++) {
    int r = wc*64 + ci*16 + m;
    int p = quad ^ ((r + (r >> 2)) & 3);
    offB[ci] = r*64 + p*16;
  }

  f32x4 acc[4][4];
  #pragma unroll
  for (int i = 0; i < 4; i++)
    #pragma unroll
    for (int j = 0; j < 4; j++) acc[i][j] = (f32x4)0.f;

  stage_tile(src, DC, dst, rr, cc);

  for (int it = 0; it < 8; ++it) {
    __syncthreads();                           // drains stage(it) (issued 1 iter ago)
    if (it < 7) stage_tile(src + (it+1)*32, DC, dst + ((it+1)&1)*4096, rr, cc);
    const int bo = (it & 1) << 13;

    short8 bh[4], bl[4];
    #pragma unroll
    for (int ci = 0; ci < 4; ci++) {
      bh[ci] = *(const short8*)((const char*)Bs_hi + bo + offB[ci]);
      bl[ci] = *(const short8*)((const char*)Bs_lo + bo + offB[ci]);
    }
    #pragma unroll
    for (int ri = 0; ri < 4; ri++) {
      short8 ah = *(const short8*)((const char*)As_hi + bo + offA[ri]);
      short8 al = *(const short8*)((const char*)As_lo + bo + offA[ri]);
      #pragma unroll
      for (int ci = 0; ci < 4; ci++) {
        acc[ri][ci] = __builtin_amdgcn_mfma_f32_16x16x32_bf16(ah, bh[ci], acc[ri][ci], 0, 0, 0);
        acc[ri][ci] = __builtin_amdgcn_mfma_f32_16x16x32_bf16(al, bh[ci], acc[ri][ci], 0, 0, 0);
        acc[ri][ci] = __builtin_amdgcn_mfma_f32_16x16x32_bf16(ah, bl[ci], acc[ri][ci], 0, 0, 0);
      }
    }
  }

  #pragma unroll
  for (int ri = 0; ri < 4; ri++) {
    #pragma unroll
    for (int reg = 0; reg < 4; reg++) {
      int r_loc = wr*64 + ri*16 + quad*4 + reg;
      float e2 = sE2[r_loc];
      unsigned long long best = 0xFFFFFFFFFFFFFFFFull;
      #pragma unroll
      for (int ci = 0; ci < 4; ci++) {
        int j_loc = wc*64 + ci*16 + m;
        float d = e2 - 2.0f * acc[ri][ci][reg];
        d = d + sN2[j_loc];
        unsigned long long key =
            ((unsigned long long)__float_as_uint(d) << 32) | (unsigned)(j0 + j_loc);
        best = key < best ? key : best;
      }
      #pragma unroll
      for (int off = 1; off < 16; off <<= 1) {
        unsigned long long o = __shfl_xor(best, off);
        best = o < best ? o : best;
      }
      if (m == 0) atomicMin(&rkey[r_loc], best);
    }
  }
  __syncthreads();
  if (tid < 128) atomicMin(&keys[(size_t)b*TT + t0 + tid], rkey[tid]);
}

// ---------------- losses + indices ----------------
__global__ void k_lossidx(const float* __restrict__ ze, const float* __restrict__ cb,
                          const unsigned long long* __restrict__ keys,
                          float* __restrict__ loss_sums, float* __restrict__ out_idx)
{
  __shared__ float sb[4];
  __shared__ int sj[64];
  int b = blockIdx.y, t0 = blockIdx.x * 64;
  int tid = threadIdx.x;
  if (tid < 64) {
    unsigned long long k = keys[(size_t)b*TT + t0 + tid];
    int j = (int)(unsigned)(k & 0xFFFFFFFFull);
    sj[tid] = j;
    out_idx[(size_t)b*TT + t0 + tid] = (float)j;
  }
  __syncthreads();
  int tt = tid & 63, tc = tid >> 6;
  const float* zb = ze + (size_t)b*DC*TT + t0;
  int j = sj[tt];
  float s = 0.f;
  for (int ci = 0; ci < 64; ci++) {
    int c = tc + ci*4;
    float zev = zb[(size_t)c*TT + tt];
    float zqv = cb[(size_t)j*DC + c];
    float d = zev - zqv;
    s += d*d;
  }
  s = block_reduce_sum_256(s, sb);
  if (tid == 0) atomicAdd(&loss_sums[b], s);
}

__global__ void k_losswrite(const float* __restrict__ loss_sums, float* __restrict__ out_loss) {
  int i = threadIdx.x;
  if (i < 8) {
    float v = loss_sums[i] * (1.f/1048576.f);
    out_loss[i] = v;
    out_loss[8 + i] = v;
  }
}

// ---------------- output gather ----------------
__global__ void k_outgather(const float* __restrict__ W2T,
                            const unsigned long long* __restrict__ keys,
                            const float* __restrict__ out_b, float* __restrict__ out)
{
  __shared__ float tile[64][65];
  __shared__ int sj[64];
  int b = blockIdx.y, t0 = blockIdx.x * 64;
  int tid = threadIdx.x;
  if (tid < 64) sj[tid] = (int)(unsigned)(keys[(size_t)b*TT + t0 + tid] & 0xFFFFFFFFull);
  __syncthreads();
  float* ob = out + (size_t)b*DIN*TT;
  int dd = tid & 63, tq = tid >> 6;
  for (int d0 = 0; d0 < DIN; d0 += 64) {
    #pragma unroll
    for (int i = 0; i < 16; i++) {
      int t = tq*16 + i;
      tile[t][dd] = W2T[(size_t)sj[t]*DIN + d0 + dd];
    }
    __syncthreads();
    #pragma unroll
    for (int i = 0; i < 16; i++) {
      int d = tq*16 + i;
      ob[(size_t)(d0+d)*TT + t0 + dd] = tile[dd][d] + out_b[d0+d];
    }
    __syncthreads();
  }
}

// ---------------- launch ----------------
extern "C" void kernel_launch(void* const* d_in, const int* in_sizes, int n_in,
                              void* d_out, int out_size, void* d_ws, size_t ws_size,
                              hipStream_t stream) {
  const float* z        = (const float*)d_in[0];
  const float* in_v     = (const float*)d_in[1];
  const float* in_g     = (const float*)d_in[2];
  const float* in_b     = (const float*)d_in[3];
  const float* out_v    = (const float*)d_in[4];
  const float* out_g    = (const float*)d_in[5];
  const float* out_b    = (const float*)d_in[6];
  const float* codebook = (const float*)d_in[7];

  char* w = (char*)d_ws;
  float* w_in   = (float*)(w + OFF_WIN);
  float* w_outT = (float*)(w + OFF_WOUTT);
  ushort_t* cb_hi = (ushort_t*)(w + OFF_CBN);
  ushort_t* cb_lo = cb_hi + (size_t)CS*DC;
  float* nrm2   = (float*)(w + OFF_NRM2);
  float* z_e    = (float*)(w + OFF_ZE);
  float* inv    = (float*)(w + OFF_INV);
  float* enc2   = (float*)(w + OFF_ENC2);
  unsigned long long* keys = (unsigned long long*)(w + OFF_KEYS);
  float* loss_sums = (float*)(w + OFF_LOSS);
  ushort_t* w_hi = (ushort_t*)(w + OFF_WSPL);
  ushort_t* w_lo = w_hi + (size_t)DC*DIN;
  // region at OFF_W2T: zT hi/lo during z_e GEMM; then enc hi/lo; then W2T.
  ushort_t* zt_hi = (ushort_t*)(w + OFF_W2T);
  ushort_t* zt_lo = zt_hi + (size_t)BB*TT*DIN;
  ushort_t* enc_hi = (ushort_t*)(w + OFF_W2T);
  ushort_t* enc_lo = enc_hi + (size_t)BB*TT*DC;
  float* W2T    = (float*)(w + OFF_W2T);

  float* out      = (float*)d_out;
  float* out_loss = out + (size_t)BB*DIN*TT;
  float* out_idx  = out_loss + 16;

  hipMemsetAsync(keys, 0xFF, 32768ull*8, stream);
  hipMemsetAsync(loss_sums, 0, 32, stream);

  k_prep_win <<<256, 256, 0, stream>>>(in_v, in_g, w_in, w_hi, w_lo);
  k_prep_wout<<<1024, 256, 0, stream>>>(out_v, out_g, w_outT);
  k_prep_cb  <<<8192, 256, 0, stream>>>(codebook, cb_hi, cb_lo, nrm2);

  if (ws_size >= REQ_WS_ZE) {
    // MFMA path: split z, then split-bf16 MFMA GEMM for z_e
    k_split_z<<<dim3(64, 16, 8), 256, 0, stream>>>(z, zt_hi, zt_lo);
    k_ze_mfma<<<dim3(32, 2, 8), 256, 0, stream>>>(zt_hi, zt_lo, w_hi, w_lo, in_b, z_e);
  } else {
    // fallback: fp32 GEMM
    k_gemm<true><<<dim3(32, 2, 8), 256, 0, stream>>>(
        w_in, z, in_b, z_e, 1024, 1024, 4096, 4096,
        (size_t)DIN*TT, (size_t)DC*TT);
  }

  k_colnorm<<<128, 256, 0, stream>>>(z_e, inv, enc2);
  k_split_enc<<<dim3(64, 4, 8), 256, 0, stream>>>(z_e, inv, enc_hi, enc_lo);

  k_dist_mfma<<<dim3(64, 32, 8), 256, 0, stream>>>(
      enc_hi, enc_lo, cb_hi, cb_lo, nrm2, enc2, keys);

  // W2T[j][d] = codebook (8192x256) @ w_outT (256x1024) — overwrites enc region
  k_gemm<false><<<dim3(8, 64, 1), 256, 0, stream>>>(
      codebook, w_outT, nullptr, W2T, 256, 256, 1024, 1024,
      (size_t)0, (size_t)0);

  k_lossidx<<<dim3(64, 8), 256, 0, stream>>>(z_e, codebook, keys, loss_sums, out_idx);
  k_losswrite<<<1, 64, 0, stream>>>(loss_sums, out_loss);
  k_outgather<<<dim3(64, 8), 256, 0, stream>>>(W2T, keys, out_b, out);
}